// Round 9
// baseline (131.345 us; speedup 1.0000x reference)
//
#include <hip/hip_runtime.h>
#include <hip/hip_bf16.h>

typedef __attribute__((ext_vector_type(8))) short bf16x8;
typedef __attribute__((ext_vector_type(16))) float f32x16;
typedef __attribute__((ext_vector_type(4))) float f32x4;
typedef __attribute__((ext_vector_type(4))) short short4v;

#define MFMA16(a, b, c) __builtin_amdgcn_mfma_f32_16x16x32_bf16(a, b, c, 0, 0, 0)
#define MFMA32(a, b, c) __builtin_amdgcn_mfma_f32_32x32x16_bf16(a, b, c, 0, 0, 0)

constexpr float kQScale = 0.18033688011112042f;  // 0.125 * log2(e): softmax in log2 domain

__device__ __forceinline__ short f2bf(float f) {
  union { float f; unsigned u; } x; x.f = f;
  unsigned r = x.u + 0x7fffu + ((x.u >> 16) & 1u);
  return (short)(r >> 16);
}

__device__ __forceinline__ unsigned pk2(float a, float b) {
  __hip_bfloat162 h = __float22bfloat162_rn(make_float2(a, b));
  union { __hip_bfloat162 h; unsigned u; } c; c.h = h;
  return c.u;
}

__device__ __forceinline__ float fast_exp2(float x) {
  float r; asm("v_exp_f32 %0, %1" : "=v"(r) : "v"(x)); return r;
}

__device__ __forceinline__ void ld16(void* lds, const void* g) {
  __builtin_amdgcn_global_load_lds((const __attribute__((address_space(1))) void*)g,
                                   (__attribute__((address_space(3))) void*)lds, 16, 0, 0);
}

// ---------------- merged convert kernel: writes X and Wio in PACKED staging layout ----------------
// Packed layout (R8-proven): per (tile, kstep) an 8KB block [128 rows][4 chunks of 8 bf16]
// with the GEMM's chunk swizzle PRE-APPLIED -> gemm0 stage reads are 1KB contiguous/wave-inst.
__global__ void conv_all(const float* __restrict__ q, const float* __restrict__ k,
                         const float* __restrict__ v, const float* __restrict__ w_in,
                         const float* __restrict__ w_out, short* __restrict__ X,
                         short* __restrict__ W) {
  int i = blockIdx.x * 256 + threadIdx.x;   // float4 index, 4194304 total
  float4 val;
  float s = 1.0f;
  short* dst;
  if (i < 3145728) {                        // qkv: 3 x 1048576
    int r = i >> 20, off = i & 0xFFFFF;
    const float* src = (r == 0) ? q : (r == 1) ? k : v;
    val = ((const float4*)src)[off];
    int m = off >> 8;                       // row 0..4095
    int kk = (off & 255) * 4;               // k element 0..1020, step 4
    int row = m & 127, mt = m >> 7;
    int ks = kk >> 5;
    int cs = ((kk >> 3) & 3) ^ ((row >> 1) & 3);
    dst = X + ((size_t)(r * 1024 + mt * 32 + ks) * 4096) + row * 32 + cs * 8 + (kk & 7);
  } else {                                  // weights: 1048576
    int j = i - 3145728;
    if (j < 786432) {
      val = ((const float4*)w_in)[j];
      if (j < 262144) s = kQScale;          // Wq rows (n < 1024)
      int n = j >> 8, kk = (j & 255) * 4;
      int row = n & 127, ntl = n >> 7;
      int ks = kk >> 5;
      int cs = ((kk >> 3) & 3) ^ ((row >> 1) & 3);
      dst = W + ((size_t)(ntl * 32 + ks) * 4096) + row * 32 + cs * 8 + (kk & 7);
    } else {
      val = ((const float4*)w_out)[j - 786432];
      dst = W + (size_t)j * 4;              // linear, beyond the 3145728-short packed region
    }
  }
  short4v o;
  o.x = f2bf(val.x * s); o.y = f2bf(val.y * s); o.z = f2bf(val.z * s); o.w = f2bf(val.w * s);
  *(short4v*)dst = o;
}

// ---------------- NT GEMM: R0-proven body; MODE 0 stages from packed layout (R8-proven) ----------------
template <int MODE>
__global__ __launch_bounds__(256) void gemm_nt(
    const short* __restrict__ A, const short* __restrict__ B,
    const float* __restrict__ bias, float* __restrict__ fout,
    short* __restrict__ q_ws, short* __restrict__ k_ws, short* __restrict__ vt_ws) {
  const int K = 1024;
  __shared__ __align__(16) short As[4096];
  __shared__ __align__(16) short Bs[4096];
  int tid = threadIdx.x;
  int w = tid >> 6, lane = tid & 63, g = lane >> 4, ln = lane & 15;
  int wr = w >> 1, wc = w & 1;

  int n0, m0, z = 0;
  if (MODE == 0) {
    // flat 768: n_sub = fid/96, z = (fid%96)>>5, m = fid&31; sharers differ by 96 (mod 8 == 0)
    int fid = blockIdx.x;
    int n_sub = fid / 96;
    int r = fid % 96;
    z = r >> 5;
    int m = r & 31;
    n0 = (z * 8 + n_sub) * 128;
    m0 = m * 128;
  } else {
    int fid = blockIdx.x;
    n0 = (fid >> 5) * 128;
    m0 = (fid & 31) * 128;
  }

  // staging sources
  const short *ag0 = nullptr, *ag1 = nullptr, *bg0 = nullptr, *bg1 = nullptr;
  const short *aps = nullptr, *bps = nullptr;   // packed-mode bases (per-lane)
  if (MODE == 0) {
    aps = A + (size_t)(z * 1024 + (m0 >> 7) * 32) * 4096 + w * 512 + lane * 8;
    bps = B + (size_t)((n0 >> 7) * 32) * 4096 + w * 512 + lane * 8;
  } else {
    int srow = w * 16 + (lane >> 2);
    int sch = (lane & 3) ^ ((srow >> 1) & 3);
    ag0 = A + (size_t)(m0 + srow) * K + sch * 8;
    ag1 = ag0 + (size_t)64 * K;
    bg0 = B + (size_t)(n0 + srow) * K + sch * 8;
    bg1 = bg0 + (size_t)64 * K;
  }
  short* asd = As + w * 512;
  short* bsd = Bs + w * 512;

  f32x4 acc[4][4];
#pragma unroll
  for (int i = 0; i < 4; ++i)
#pragma unroll
    for (int j = 0; j < 4; ++j) acc[i][j] = (f32x4){0.f, 0.f, 0.f, 0.f};

  int rsw = (ln >> 1) & 3;                            // read-side chunk swizzle
  for (int kb = 0; kb < K; kb += 32) {
    __syncthreads();
    if (MODE == 0) {
      const short* ap = aps + (size_t)(kb >> 5) * 4096;
      const short* bp = bps + (size_t)(kb >> 5) * 4096;
      ld16(asd,        ap);
      ld16(asd + 2048, ap + 2048);
      ld16(bsd,        bp);
      ld16(bsd + 2048, bp + 2048);
    } else {
      ld16(asd,        ag0 + kb);
      ld16(asd + 2048, ag1 + kb);
      ld16(bsd,        bg0 + kb);
      ld16(bsd + 2048, bg1 + kb);
    }
    __syncthreads();
    bf16x8 af[4], bfr[4];
#pragma unroll
    for (int fm = 0; fm < 4; ++fm)
      af[fm] = *(const bf16x8*)&As[(wr * 64 + fm * 16 + ln) * 32 + (g ^ rsw) * 8];
#pragma unroll
    for (int fn = 0; fn < 4; ++fn)
      bfr[fn] = *(const bf16x8*)&Bs[(wc * 64 + fn * 16 + ln) * 32 + (g ^ rsw) * 8];
#pragma unroll
    for (int fm = 0; fm < 4; ++fm)
#pragma unroll
      for (int fn = 0; fn < 4; ++fn) acc[fm][fn] = MFMA16(af[fm], bfr[fn], acc[fm][fn]);
  }

#pragma unroll
  for (int fm = 0; fm < 4; ++fm) {
#pragma unroll
    for (int fn = 0; fn < 4; ++fn) {
      int col = n0 + wc * 64 + fn * 16 + ln;
#pragma unroll
      for (int i = 0; i < 4; ++i) {
        int m = m0 + wr * 64 + fm * 16 + g * 4 + i;
        float val = acc[fm][fn][i];
        if (MODE == 1) {
          fout[(size_t)m * 1024 + col] = val + bias[col];
        } else {
          int zc = col >> 10;
          int oe = col & 1023;
          float bval = bias[col];
          if (zc == 0) bval *= kQScale;
          short bv = f2bf(val + bval);
          int hh = oe >> 6, d = oe & 63;
          int l = m >> 1, nb = m & 1;
          int nh = nb * 16 + hh;
          if (zc == 0)      q_ws[((size_t)nh * 2048 + l) * 64 + d] = bv;
          else if (zc == 1) k_ws[((size_t)nh * 2048 + l) * 64 + d] = bv;
          else {
            int u = l & 15;
            int lp = (l & ~15) | (u & 3) | ((u & 4) << 1) | ((u & 8) >> 1);
            vt_ws[((size_t)nh * 64 + d) * 2048 + lp] = bv;
          }
        }
      }
    }
  }
}

// ---------------- flash attention v6: 8 waves/block, 256 q-rows share staged K/V ----------------
// R9 change: merge the two co-resident 4-wave blocks into one 8-wave block (grid 512->256,
// 512 threads). Staged K/V bytes HALVE (262MB -> 131MB) since 256 q-rows share each tile.
// Staging is now ONE full-tile call (512 thr x 16B = 8KB); counted vmcnt recomputed:
// steady vmcnt(2) (outstanding = {K(t+3), V(t+2)}), tail 1, 0. All swizzle formulas are
// row-mod-8-invariant so rA = tid>>3 in 0..63 needs no other change.
struct AttnCtx {
  const char* kg; const char* vg;      // next global stage pointers (lane addr)
  char* klB; char* vlB;                // LDS bases
  char* kdst; char* vdst;              // wave-uniform LDS stage dest bases
  int lq, hi, swq;
  float lr;
};

__device__ __forceinline__ void attn_iter(
    int t, int& ksl, AttnCtx& c,
    f32x16& sCA, f32x16& sCB, f32x16& sNA, f32x16& sNB,
    f32x16 (&accO)[2], const bf16x8 (&qf)[4]) {
  // A: issue stages (K t+3, V t+2) — one full-tile call each (512 threads cover 64 rows)
  if (t <= 28) {
    ld16(c.kdst + ksl * 8192, c.kg);
    c.kg += 8192;
  }
  if (t <= 29) {
    int vs = ksl + 2; if (vs >= 3) vs -= 3;
    ld16(c.vdst + vs * 8192, c.vg);
    c.vg += 128;
  }

  // E': issue QK(t+1) MFMAs (independent of softmax below -> overlaps)
  if (t < 31) {
    int kr = ksl == 2 ? 0 : ksl + 1;
    const char* Kt = c.klB + kr * 8192;
#pragma unroll
    for (int i = 0; i < 16; ++i) { sNA[i] = 0.f; sNB[i] = 0.f; }
    __builtin_amdgcn_s_setprio(1);
#pragma unroll
    for (int kd = 0; kd < 4; ++kd) {
      int x = (32 * kd + 16 * c.hi) ^ c.swq;
      bf16x8 k0 = *(const bf16x8*)(Kt + c.lq * 128 + x);
      bf16x8 k1 = *(const bf16x8*)(Kt + (32 + c.lq) * 128 + x);
      sNA = MFMA32(k0, qf[kd], sNA);
      sNB = MFMA32(k1, qf[kd], sNB);
    }
    __builtin_amdgcn_s_setprio(0);
  }

  // B: static softmax on S(t): p = 2^s (shift-invariant; scores bounded)
#pragma unroll
  for (int i = 0; i < 16; ++i) { sCA[i] = fast_exp2(sCA[i]); sCB[i] = fast_exp2(sCB[i]); }
  float a0 = 0.f, a1 = 0.f, a2 = 0.f, a3 = 0.f;
#pragma unroll
  for (int i = 0; i < 4; ++i) {
    a0 += sCA[4 * i] + sCB[4 * i];
    a1 += sCA[4 * i + 1] + sCB[4 * i + 1];
    a2 += sCA[4 * i + 2] + sCB[4 * i + 2];
    a3 += sCA[4 * i + 3] + sCB[4 * i + 3];
  }
  c.lr += (a0 + a1) + (a2 + a3);

  bf16x8 pf[2][2];
  union PU { unsigned u[4]; bf16x8 v; };
#pragma unroll
  for (int ks = 0; ks < 2; ++ks) {
    PU a, b;
#pragma unroll
    for (int i = 0; i < 4; ++i) {
      a.u[i] = pk2(sCA[ks * 8 + 2 * i], sCA[ks * 8 + 2 * i + 1]);
      b.u[i] = pk2(sCB[ks * 8 + 2 * i], sCB[ks * 8 + 2 * i + 1]);
    }
    pf[0][ks] = a.v;
    pf[1][ks] = b.v;
  }

  // C: PV(t)
  const char* Vtl = c.vlB + ksl * 8192;
  __builtin_amdgcn_s_setprio(1);
#pragma unroll
  for (int dblk = 0; dblk < 2; ++dblk) {
    const char* vrow = Vtl + (dblk * 32 + c.lq) * 128;
#pragma unroll
    for (int sblk = 0; sblk < 2; ++sblk) {
#pragma unroll
      for (int ks = 0; ks < 2; ++ks) {
        bf16x8 vf = *(const bf16x8*)(vrow + ((sblk * 64 + ks * 32 + c.hi * 16) ^ c.swq));
        accO[dblk] = MFMA32(vf, pf[sblk][ks], accO[dblk]);
      }
    }
  }
  __builtin_amdgcn_s_setprio(0);

  // D: counted vmem wait (never 0 in steady state) + raw barrier
  // FIFO audit: at end of iter t outstanding = {K(t+3), V(t+2)} -> vmcnt(2);
  // t==29: {V31} after needing K31,V30 -> vmcnt(1); t==30: need V31 -> vmcnt(0).
  if (t < 29)       asm volatile("s_waitcnt vmcnt(2)" ::: "memory");
  else if (t == 29) asm volatile("s_waitcnt vmcnt(1)" ::: "memory");
  else if (t == 30) asm volatile("s_waitcnt vmcnt(0)" ::: "memory");
  if (t < 31) __builtin_amdgcn_s_barrier();

  ksl = ksl == 2 ? 0 : ksl + 1;
}

__global__ __launch_bounds__(512) void attn5(const short* __restrict__ Qws,
                                             const short* __restrict__ Kws,
                                             const short* __restrict__ Vt,
                                             short* __restrict__ Ows) {
  const int L = 2048;
  int bid = blockIdx.x;
  int nh = bid & 31, qt = bid >> 5;          // 8 q-tiles x 32 heads = 256 blocks
  int nb = nh >> 4, h = nh & 15;
  int tid = threadIdx.x;
  int w = tid >> 6, lane = tid & 63;         // 8 waves
  int lq = lane & 31, hi = lane >> 5;

  __shared__ __align__(16) char Kl[3][8192];   // [64 s][64 d], XOR-swizzled rows
  __shared__ __align__(16) char Vl[3][8192];   // [64 d][64 s-permuted], XOR-swizzled rows

  int q0 = qt * 256 + w * 32;                  // 8 waves x 32 q-rows = 256 rows/block
  const short* Qb = Qws + (size_t)nh * L * 64;
  const char* Kb = (const char*)(Kws + (size_t)nh * L * 64);
  const char* Vb = (const char*)(Vt + (size_t)nh * 64 * L);

  bf16x8 qf[4];
#pragma unroll
  for (int kd = 0; kd < 4; ++kd)
    qf[kd] = *(const bf16x8*)(Qb + (size_t)(q0 + lq) * 64 + kd * 16 + hi * 8);

  // staging: 512 threads cover all 64 tile rows in one call (rA = tid>>3 in 0..63)
  int rA = tid >> 3, cc = (tid & 7) * 16;
  int swr = (rA & 7) << 4;                     // row-mod-8 swizzle (matches read side)

  AttnCtx c;
  c.kg = Kb + rA * 128 + (cc ^ swr);
  c.vg = Vb + rA * 4096 + (cc ^ swr);
  c.klB = (char*)&Kl[0][0];
  c.vlB = (char*)&Vl[0][0];
  c.kdst = c.klB + w * 1024;                   // 8 waves x 1KB = full 8KB tile
  c.vdst = c.vlB + w * 1024;
  c.lq = lq; c.hi = hi; c.swq = (lq & 7) << 4;
  c.lr = 0.f;

  // prologue stages: K0,K1,V0,K2,V1 (5 vmem calls)
  ld16(c.kdst,         c.kg);
  ld16(c.kdst + 8192,  c.kg + 8192);
  ld16(c.vdst,         c.vg);
  ld16(c.kdst + 16384, c.kg + 16384);
  ld16(c.vdst + 8192,  c.vg + 128);
  c.kg += 3 * 8192;
  c.vg += 2 * 128;

  f32x16 accO[2];
#pragma unroll
  for (int i = 0; i < 16; ++i) { accO[0][i] = 0.f; accO[1][i] = 0.f; }
  f32x16 s0A, s0B, s1A, s1B;

  asm volatile("s_waitcnt vmcnt(2)" ::: "memory");   // K0,K1,V0 arrived; K2,V1 in flight
  __builtin_amdgcn_s_barrier();

  // prologue QK(0) -> s0
#pragma unroll
  for (int i = 0; i < 16; ++i) { s0A[i] = 0.f; s0B[i] = 0.f; }
  __builtin_amdgcn_s_setprio(1);
#pragma unroll
  for (int kd = 0; kd < 4; ++kd) {
    int x = (32 * kd + 16 * hi) ^ c.swq;
    bf16x8 k0 = *(const bf16x8*)(c.klB + lq * 128 + x);
    bf16x8 k1 = *(const bf16x8*)(c.klB + (32 + lq) * 128 + x);
    s0A = MFMA32(k0, qf[kd], s0A);
    s0B = MFMA32(k1, qf[kd], s0B);
  }
  __builtin_amdgcn_s_setprio(0);

  // seam barrier (race fix): orders all waves' slot-0 reads before iter-0's
  // K3 stage into slot 0.
  __builtin_amdgcn_s_barrier();

  int ksl = 0;
  for (int it = 0; it < 16; ++it) {
    attn_iter(2 * it,     ksl, c, s0A, s0B, s1A, s1B, accO, qf);
    attn_iter(2 * it + 1, ksl, c, s1A, s1B, s0A, s0B, accO, qf);
  }

  // epilogue: l = own half + partner half; O[q][d] = acc / l
  float lr = c.lr + __shfl_xor(c.lr, 32);
  float inv = 1.0f / lr;
  int qrow = q0 + lq;
  short* orow = Ows + (size_t)(qrow * 2 + nb) * 1024 + h * 64;
#pragma unroll
  for (int dblk = 0; dblk < 2; ++dblk) {
#pragma unroll
    for (int grp = 0; grp < 4; ++grp) {
      short4v o;
      o.x = f2bf(accO[dblk][grp * 4 + 0] * inv);
      o.y = f2bf(accO[dblk][grp * 4 + 1] * inv);
      o.z = f2bf(accO[dblk][grp * 4 + 2] * inv);
      o.w = f2bf(accO[dblk][grp * 4 + 3] * inv);
      *(short4v*)(orow + dblk * 32 + grp * 8 + hi * 4) = o;
    }
  }
}

// ---------------- launch ----------------
extern "C" void kernel_launch(void* const* d_in, const int* in_sizes, int n_in,
                              void* d_out, int out_size, void* d_ws, size_t ws_size,
                              hipStream_t stream) {
  const float* q     = (const float*)d_in[0];
  const float* k     = (const float*)d_in[1];
  const float* v     = (const float*)d_in[2];
  const float* w_in  = (const float*)d_in[3];
  const float* b_in  = (const float*)d_in[4];
  const float* w_out = (const float*)d_in[5];
  const float* b_out = (const float*)d_in[6];
  float* out = (float*)d_out;
  char* ws = (char*)d_ws;

  short* X    = (short*)(ws);                  // 3*4096*1024 bf16 (packed staging layout)
  short* Wio  = (short*)(ws + 25165824);       // 3072*1024 (packed staging layout)
  short* Wout = (short*)(ws + 31457280);       // 1024*1024 (linear)
  short* Qws  = (short*)(ws + 33554432);       // [32 nh][2048][64]
  short* Kws  = (short*)(ws + 41943040);       // [32 nh][2048][64]
  short* Vt   = (short*)(ws + 50331648);       // [32 nh][64][2048] (s-permuted)
  short* Ows  = (short*)(ws + 58720256);       // [4096][1024]

  conv_all<<<16384, 256, 0, stream>>>(q, k, v, w_in, w_out, X, Wio);
  gemm_nt<0><<<768, 256, 0, stream>>>(X, Wio, b_in, nullptr, Qws, Kws, Vt);
  attn5<<<256, 512, 0, stream>>>(Qws, Kws, Vt, Ows);
  gemm_nt<1><<<256, 256, 0, stream>>>(Ows, Wout, b_out, out, nullptr, nullptr, nullptr);
}

// Round 10
// 122.561 us; speedup vs baseline: 1.0717x; 1.0717x over previous
//
#include <hip/hip_runtime.h>
#include <hip/hip_bf16.h>

typedef __attribute__((ext_vector_type(8))) short bf16x8;
typedef __attribute__((ext_vector_type(16))) float f32x16;
typedef __attribute__((ext_vector_type(4))) float f32x4;
typedef __attribute__((ext_vector_type(4))) short short4v;

#define MFMA16(a, b, c) __builtin_amdgcn_mfma_f32_16x16x32_bf16(a, b, c, 0, 0, 0)
#define MFMA32(a, b, c) __builtin_amdgcn_mfma_f32_32x32x16_bf16(a, b, c, 0, 0, 0)

constexpr float kQScale = 0.18033688011112042f;  // 0.125 * log2(e): softmax in log2 domain

__device__ __forceinline__ short f2bf(float f) {
  union { float f; unsigned u; } x; x.f = f;
  unsigned r = x.u + 0x7fffu + ((x.u >> 16) & 1u);
  return (short)(r >> 16);
}

__device__ __forceinline__ unsigned pk2(float a, float b) {
  __hip_bfloat162 h = __float22bfloat162_rn(make_float2(a, b));
  union { __hip_bfloat162 h; unsigned u; } c; c.h = h;
  return c.u;
}

__device__ __forceinline__ float fast_exp2(float x) {
  float r; asm("v_exp_f32 %0, %1" : "=v"(r) : "v"(x)); return r;
}

__device__ __forceinline__ void ld16(void* lds, const void* g) {
  __builtin_amdgcn_global_load_lds((const __attribute__((address_space(1))) void*)g,
                                   (__attribute__((address_space(3))) void*)lds, 16, 0, 0);
}

// ---------------- merged convert kernel: packed staging layouts for X, Wio AND Wout ----------------
// Packed layout (R8-proven): per (tile, kstep) an 8KB block [128 rows][4 chunks of 8 bf16]
// with the GEMM's chunk swizzle PRE-APPLIED -> GEMM stage reads are 1KB contiguous/wave-inst.
// X   : [z 0..2][mtile 0..31][kstep 0..31] blocks (24MB)
// Wio : [ntile 0..23][kstep 0..31] blocks (6MB)
// Wout: [ntile 0..7][kstep 0..31] blocks (2MB), base = W + 3145728 shorts
__global__ void conv_all(const float* __restrict__ q, const float* __restrict__ k,
                         const float* __restrict__ v, const float* __restrict__ w_in,
                         const float* __restrict__ w_out, short* __restrict__ X,
                         short* __restrict__ W) {
  int i = blockIdx.x * 256 + threadIdx.x;   // float4 index, 4194304 total
  float4 val;
  float s = 1.0f;
  short* dst;
  if (i < 3145728) {                        // qkv: 3 x 1048576
    int r = i >> 20, off = i & 0xFFFFF;
    const float* src = (r == 0) ? q : (r == 1) ? k : v;
    val = ((const float4*)src)[off];
    int m = off >> 8;                       // row 0..4095
    int kk = (off & 255) * 4;               // k element 0..1020, step 4
    int row = m & 127, mt = m >> 7;
    int ks = kk >> 5;
    int cs = ((kk >> 3) & 3) ^ ((row >> 1) & 3);
    dst = X + ((size_t)(r * 1024 + mt * 32 + ks) * 4096) + row * 32 + cs * 8 + (kk & 7);
  } else {                                  // weights: 1048576
    int j = i - 3145728;
    if (j < 786432) {
      val = ((const float4*)w_in)[j];
      if (j < 262144) s = kQScale;          // Wq rows (n < 1024)
      int n = j >> 8, kk = (j & 255) * 4;
      int row = n & 127, ntl = n >> 7;
      int ks = kk >> 5;
      int cs = ((kk >> 3) & 3) ^ ((row >> 1) & 3);
      dst = W + ((size_t)(ntl * 32 + ks) * 4096) + row * 32 + cs * 8 + (kk & 7);
    } else {
      int jj = j - 786432;                  // 0..262143
      val = ((const float4*)w_out)[jj];
      int n = jj >> 8, kk = (jj & 255) * 4;
      int row = n & 127, ntl = n >> 7;      // ntl 0..7
      int ks = kk >> 5;
      int cs = ((kk >> 3) & 3) ^ ((row >> 1) & 3);
      dst = W + 3145728 + ((size_t)(ntl * 32 + ks) * 4096) + row * 32 + cs * 8 + (kk & 7);
    }
  }
  short4v o;
  o.x = f2bf(val.x * s); o.y = f2bf(val.y * s); o.z = f2bf(val.z * s); o.w = f2bf(val.w * s);
  *(short4v*)dst = o;
}

// ---------------- NT GEMM: R0-proven body; BOTH modes stage from packed layouts ----------------
// MODE 0: A = X packed (z,mtile,kstep), B = Wio packed (ntile,kstep).   [R8-proven]
// MODE 1: A = Ows packed (mtile,kstep) written by attn, B = Wout packed.
// LDS contents identical to the original scattered path (swizzle baked into the pack).
template <int MODE>
__global__ __launch_bounds__(256) void gemm_nt(
    const short* __restrict__ A, const short* __restrict__ B,
    const float* __restrict__ bias, float* __restrict__ fout,
    short* __restrict__ q_ws, short* __restrict__ k_ws, short* __restrict__ vt_ws) {
  const int K = 1024;
  __shared__ __align__(16) short As[4096];
  __shared__ __align__(16) short Bs[4096];
  int tid = threadIdx.x;
  int w = tid >> 6, lane = tid & 63, g = lane >> 4, ln = lane & 15;
  int wr = w >> 1, wc = w & 1;

  int n0, m0, z = 0;
  if (MODE == 0) {
    // flat 768: n_sub = fid/96, z = (fid%96)>>5, m = fid&31; sharers differ by 96 (mod 8 == 0)
    int fid = blockIdx.x;
    int n_sub = fid / 96;
    int r = fid % 96;
    z = r >> 5;
    int m = r & 31;
    n0 = (z * 8 + n_sub) * 128;
    m0 = m * 128;
  } else {
    int fid = blockIdx.x;
    n0 = (fid >> 5) * 128;
    m0 = (fid & 31) * 128;
  }

  // packed staging bases (per-lane): contiguous 1KB per wave-inst
  const short* aps;
  const short* bps;
  if (MODE == 0) {
    aps = A + (size_t)(z * 1024 + (m0 >> 7) * 32) * 4096 + w * 512 + lane * 8;
    bps = B + (size_t)(((n0 >> 7)) * 32) * 4096 + w * 512 + lane * 8;
  } else {
    aps = A + (size_t)((m0 >> 7) * 32) * 4096 + w * 512 + lane * 8;
    bps = B + (size_t)((n0 >> 7) * 32) * 4096 + w * 512 + lane * 8;
  }
  short* asd = As + w * 512;
  short* bsd = Bs + w * 512;

  f32x4 acc[4][4];
#pragma unroll
  for (int i = 0; i < 4; ++i)
#pragma unroll
    for (int j = 0; j < 4; ++j) acc[i][j] = (f32x4){0.f, 0.f, 0.f, 0.f};

  int rsw = (ln >> 1) & 3;                            // read-side chunk swizzle
  for (int kb = 0; kb < K; kb += 32) {
    __syncthreads();
    const short* ap = aps + (size_t)(kb >> 5) * 4096;
    const short* bp = bps + (size_t)(kb >> 5) * 4096;
    ld16(asd,        ap);
    ld16(asd + 2048, ap + 2048);
    ld16(bsd,        bp);
    ld16(bsd + 2048, bp + 2048);
    __syncthreads();
    bf16x8 af[4], bfr[4];
#pragma unroll
    for (int fm = 0; fm < 4; ++fm)
      af[fm] = *(const bf16x8*)&As[(wr * 64 + fm * 16 + ln) * 32 + (g ^ rsw) * 8];
#pragma unroll
    for (int fn = 0; fn < 4; ++fn)
      bfr[fn] = *(const bf16x8*)&Bs[(wc * 64 + fn * 16 + ln) * 32 + (g ^ rsw) * 8];
#pragma unroll
    for (int fm = 0; fm < 4; ++fm)
#pragma unroll
      for (int fn = 0; fn < 4; ++fn) acc[fm][fn] = MFMA16(af[fm], bfr[fn], acc[fm][fn]);
  }

#pragma unroll
  for (int fm = 0; fm < 4; ++fm) {
#pragma unroll
    for (int fn = 0; fn < 4; ++fn) {
      int col = n0 + wc * 64 + fn * 16 + ln;
#pragma unroll
      for (int i = 0; i < 4; ++i) {
        int m = m0 + wr * 64 + fm * 16 + g * 4 + i;
        float val = acc[fm][fn][i];
        if (MODE == 1) {
          fout[(size_t)m * 1024 + col] = val + bias[col];
        } else {
          int zc = col >> 10;
          int oe = col & 1023;
          float bval = bias[col];
          if (zc == 0) bval *= kQScale;
          short bv = f2bf(val + bval);
          int hh = oe >> 6, d = oe & 63;
          int l = m >> 1, nb = m & 1;
          int nh = nb * 16 + hh;
          if (zc == 0)      q_ws[((size_t)nh * 2048 + l) * 64 + d] = bv;
          else if (zc == 1) k_ws[((size_t)nh * 2048 + l) * 64 + d] = bv;
          else {
            int u = l & 15;
            int lp = (l & ~15) | (u & 3) | ((u & 4) << 1) | ((u & 8) >> 1);
            vt_ws[((size_t)nh * 64 + d) * 2048 + lp] = bv;
          }
        }
      }
    }
  }
}

// ---------------- flash attention v5 (R8-proven: 4 waves/block, 2 blocks/CU) ----------------
// R10: compute schedule EXACTLY as R8 (58.5us measured). Only the epilogue changes:
// Ows is written in the packed [mtile][kstep] staging layout consumed by gemm_nt<1>.
struct AttnCtx {
  const char* kg; const char* vg;      // next global stage pointers (call-A lane addr)
  char* klB; char* vlB;                // LDS bases
  char* kdst; char* vdst;              // wave-uniform LDS stage dest bases
  int lq, hi, swq;
  float lr;
};

__device__ __forceinline__ void attn_iter(
    int t, int& ksl, AttnCtx& c,
    f32x16& sCA, f32x16& sCB, f32x16& sNA, f32x16& sNB,
    f32x16 (&accO)[2], const bf16x8 (&qf)[4]) {
  // A: issue stages (K t+3, V t+2) — 2 calls each (rows 0-31 / 32-63 of the tile)
  if (t <= 28) {
    ld16(c.kdst + ksl * 8192,        c.kg);
    ld16(c.kdst + ksl * 8192 + 4096, c.kg + 4096);
    c.kg += 8192;
  }
  if (t <= 29) {
    int vs = ksl + 2; if (vs >= 3) vs -= 3;
    ld16(c.vdst + vs * 8192,        c.vg);
    ld16(c.vdst + vs * 8192 + 4096, c.vg + 131072);
    c.vg += 128;
  }

  // E': issue QK(t+1) MFMAs (independent of softmax below -> overlaps)
  if (t < 31) {
    int kr = ksl == 2 ? 0 : ksl + 1;
    const char* Kt = c.klB + kr * 8192;
#pragma unroll
    for (int i = 0; i < 16; ++i) { sNA[i] = 0.f; sNB[i] = 0.f; }
    __builtin_amdgcn_s_setprio(1);
#pragma unroll
    for (int kd = 0; kd < 4; ++kd) {
      int x = (32 * kd + 16 * c.hi) ^ c.swq;
      bf16x8 k0 = *(const bf16x8*)(Kt + c.lq * 128 + x);
      bf16x8 k1 = *(const bf16x8*)(Kt + (32 + c.lq) * 128 + x);
      sNA = MFMA32(k0, qf[kd], sNA);
      sNB = MFMA32(k1, qf[kd], sNB);
    }
    __builtin_amdgcn_s_setprio(0);
  }

  // B: static softmax on S(t): p = 2^s (shift-invariant; scores bounded)
#pragma unroll
  for (int i = 0; i < 16; ++i) { sCA[i] = fast_exp2(sCA[i]); sCB[i] = fast_exp2(sCB[i]); }
  float a0 = 0.f, a1 = 0.f, a2 = 0.f, a3 = 0.f;
#pragma unroll
  for (int i = 0; i < 4; ++i) {
    a0 += sCA[4 * i] + sCB[4 * i];
    a1 += sCA[4 * i + 1] + sCB[4 * i + 1];
    a2 += sCA[4 * i + 2] + sCB[4 * i + 2];
    a3 += sCA[4 * i + 3] + sCB[4 * i + 3];
  }
  c.lr += (a0 + a1) + (a2 + a3);

  bf16x8 pf[2][2];
  union PU { unsigned u[4]; bf16x8 v; };
#pragma unroll
  for (int ks = 0; ks < 2; ++ks) {
    PU a, b;
#pragma unroll
    for (int i = 0; i < 4; ++i) {
      a.u[i] = pk2(sCA[ks * 8 + 2 * i], sCA[ks * 8 + 2 * i + 1]);
      b.u[i] = pk2(sCB[ks * 8 + 2 * i], sCB[ks * 8 + 2 * i + 1]);
    }
    pf[0][ks] = a.v;
    pf[1][ks] = b.v;
  }

  // C: PV(t)
  const char* Vtl = c.vlB + ksl * 8192;
  __builtin_amdgcn_s_setprio(1);
#pragma unroll
  for (int dblk = 0; dblk < 2; ++dblk) {
    const char* vrow = Vtl + (dblk * 32 + c.lq) * 128;
#pragma unroll
    for (int sblk = 0; sblk < 2; ++sblk) {
#pragma unroll
      for (int ks = 0; ks < 2; ++ks) {
        bf16x8 vf = *(const bf16x8*)(vrow + ((sblk * 64 + ks * 32 + c.hi * 16) ^ c.swq));
        accO[dblk] = MFMA32(vf, pf[sblk][ks], accO[dblk]);
      }
    }
  }
  __builtin_amdgcn_s_setprio(0);

  // D: counted vmem wait (never 0 in steady state) + raw barrier
  if (t < 29)       asm volatile("s_waitcnt vmcnt(4)" ::: "memory");
  else if (t == 29) asm volatile("s_waitcnt vmcnt(2)" ::: "memory");
  else if (t == 30) asm volatile("s_waitcnt vmcnt(0)" ::: "memory");
  if (t < 31) __builtin_amdgcn_s_barrier();

  ksl = ksl == 2 ? 0 : ksl + 1;
}

__global__ __launch_bounds__(256, 2) void attn5(const short* __restrict__ Qws,
                                                const short* __restrict__ Kws,
                                                const short* __restrict__ Vt,
                                                short* __restrict__ Ows) {
  const int L = 2048;
  int bid = blockIdx.x;
  int nh = bid & 31, qt = bid >> 5;          // 16 q-tiles x 32 heads = 512 blocks
  int nb = nh >> 4, h = nh & 15;
  int tid = threadIdx.x;
  int w = tid >> 6, lane = tid & 63;
  int lq = lane & 31, hi = lane >> 5;

  __shared__ __align__(16) char Kl[3][8192];   // [64 s][64 d], XOR-swizzled rows
  __shared__ __align__(16) char Vl[3][8192];   // [64 d][64 s-permuted], XOR-swizzled rows

  int q0 = qt * 128 + w * 32;                  // 4 waves x 32 q-rows
  const short* Qb = Qws + (size_t)nh * L * 64;
  const char* Kb = (const char*)(Kws + (size_t)nh * L * 64);
  const char* Vb = (const char*)(Vt + (size_t)nh * 64 * L);

  bf16x8 qf[4];
#pragma unroll
  for (int kd = 0; kd < 4; ++kd)
    qf[kd] = *(const bf16x8*)(Qb + (size_t)(q0 + lq) * 64 + kd * 16 + hi * 8);

  // staging: call A covers tile rows 0..31 (rA = tid>>3), call B rows 32..63.
  int rA = tid >> 3, cc = (tid & 7) * 16;
  int swr = (rA & 7) << 4;                     // invariant under row+32

  AttnCtx c;
  c.kg = Kb + rA * 128 + (cc ^ swr);           // call B: +4096 (32 rows x 128B)
  c.vg = Vb + rA * 4096 + (cc ^ swr);          // call B: +131072 (32 d-rows x 4096B)
  c.klB = (char*)&Kl[0][0];
  c.vlB = (char*)&Vl[0][0];
  c.kdst = c.klB + w * 1024;
  c.vdst = c.vlB + w * 1024;
  c.lq = lq; c.hi = hi; c.swq = (lq & 7) << 4;
  c.lr = 0.f;

  // prologue stages: K0,K1,V0,K2,V1 (10 vmem ops)
  ld16(c.kdst,                c.kg);
  ld16(c.kdst + 4096,         c.kg + 4096);
  ld16(c.kdst + 8192,         c.kg + 8192);
  ld16(c.kdst + 8192 + 4096,  c.kg + 8192 + 4096);
  ld16(c.vdst,                c.vg);
  ld16(c.vdst + 4096,         c.vg + 131072);
  ld16(c.kdst + 16384,        c.kg + 16384);
  ld16(c.kdst + 16384 + 4096, c.kg + 16384 + 4096);
  ld16(c.vdst + 8192,         c.vg + 128);
  ld16(c.vdst + 8192 + 4096,  c.vg + 128 + 131072);
  c.kg += 3 * 8192;
  c.vg += 2 * 128;

  f32x16 accO[2];
#pragma unroll
  for (int i = 0; i < 16; ++i) { accO[0][i] = 0.f; accO[1][i] = 0.f; }
  f32x16 s0A, s0B, s1A, s1B;

  asm volatile("s_waitcnt vmcnt(4)" ::: "memory");   // K0,K1,V0 arrived
  __builtin_amdgcn_s_barrier();

  // prologue QK(0) -> s0
#pragma unroll
  for (int i = 0; i < 16; ++i) { s0A[i] = 0.f; s0B[i] = 0.f; }
  __builtin_amdgcn_s_setprio(1);
#pragma unroll
  for (int kd = 0; kd < 4; ++kd) {
    int x = (32 * kd + 16 * hi) ^ c.swq;
    bf16x8 k0 = *(const bf16x8*)(c.klB + lq * 128 + x);
    bf16x8 k1 = *(const bf16x8*)(c.klB + (32 + lq) * 128 + x);
    s0A = MFMA32(k0, qf[kd], s0A);
    s0B = MFMA32(k1, qf[kd], s0B);
  }
  __builtin_amdgcn_s_setprio(0);

  // seam barrier (R7 race fix): orders all waves' slot-0 reads before iter-0's
  // K3 stage into slot 0.
  __builtin_amdgcn_s_barrier();

  int ksl = 0;
  for (int it = 0; it < 16; ++it) {
    attn_iter(2 * it,     ksl, c, s0A, s0B, s1A, s1B, accO, qf);
    attn_iter(2 * it + 1, ksl, c, s1A, s1B, s0A, s0B, accO, qf);
  }

  // epilogue: l = own half + partner half; O in PACKED staging layout for gemm_nt<1>:
  // m = qrow*2+nb, col c = h*64 + dblk*32 + grp*8 + hi*4
  // block = (m>>7)*32 + (c>>5) = (m>>7)*32 + h*2 + dblk ; row = m&127 ; chunk = grp
  // dst = block*4096 + row*32 + (grp ^ ((row>>1)&3))*8 + hi*4
  float lr = c.lr + __shfl_xor(c.lr, 32);
  float inv = 1.0f / lr;
  int qrow = q0 + lq;
  int m = qrow * 2 + nb;
  int row = m & 127;
  short* obase = Ows + ((size_t)((m >> 7) * 32 + h * 2) * 4096) + row * 32 + hi * 4;
  int rs3 = (row >> 1) & 3;
#pragma unroll
  for (int dblk = 0; dblk < 2; ++dblk) {
#pragma unroll
    for (int grp = 0; grp < 4; ++grp) {
      short4v o;
      o.x = f2bf(accO[dblk][grp * 4 + 0] * inv);
      o.y = f2bf(accO[dblk][grp * 4 + 1] * inv);
      o.z = f2bf(accO[dblk][grp * 4 + 2] * inv);
      o.w = f2bf(accO[dblk][grp * 4 + 3] * inv);
      *(short4v*)(obase + dblk * 4096 + (grp ^ rs3) * 8) = o;
    }
  }
}

// ---------------- launch ----------------
extern "C" void kernel_launch(void* const* d_in, const int* in_sizes, int n_in,
                              void* d_out, int out_size, void* d_ws, size_t ws_size,
                              hipStream_t stream) {
  const float* q     = (const float*)d_in[0];
  const float* k     = (const float*)d_in[1];
  const float* v     = (const float*)d_in[2];
  const float* w_in  = (const float*)d_in[3];
  const float* b_in  = (const float*)d_in[4];
  const float* w_out = (const float*)d_in[5];
  const float* b_out = (const float*)d_in[6];
  float* out = (float*)d_out;
  char* ws = (char*)d_ws;

  short* X    = (short*)(ws);                  // 3*4096*1024 bf16 (packed staging layout)
  short* Wio  = (short*)(ws + 25165824);       // 3072*1024 (packed staging layout)
  short* Wout = (short*)(ws + 31457280);       // 1024*1024 (packed staging layout)
  short* Qws  = (short*)(ws + 33554432);       // [32 nh][2048][64]
  short* Kws  = (short*)(ws + 41943040);       // [32 nh][2048][64]
  short* Vt   = (short*)(ws + 50331648);       // [32 nh][64][2048] (s-permuted)
  short* Ows  = (short*)(ws + 58720256);       // [4096][1024] packed as [mtile][kstep] blocks

  conv_all<<<16384, 256, 0, stream>>>(q, k, v, w_in, w_out, X, Wio);
  gemm_nt<0><<<768, 256, 0, stream>>>(X, Wio, b_in, nullptr, Qws, Kws, Vt);
  attn5<<<512, 256, 0, stream>>>(Qws, Kws, Vt, Ows);
  gemm_nt<1><<<256, 256, 0, stream>>>(Ows, Wout, b_out, out, nullptr, nullptr, nullptr);
}

// Round 11
// 121.495 us; speedup vs baseline: 1.0811x; 1.0088x over previous
//
#include <hip/hip_runtime.h>
#include <hip/hip_bf16.h>

typedef __attribute__((ext_vector_type(8))) short bf16x8;
typedef __attribute__((ext_vector_type(16))) float f32x16;
typedef __attribute__((ext_vector_type(4))) float f32x4;
typedef __attribute__((ext_vector_type(4))) short short4v;

#define MFMA16(a, b, c) __builtin_amdgcn_mfma_f32_16x16x32_bf16(a, b, c, 0, 0, 0)
#define MFMA32(a, b, c) __builtin_amdgcn_mfma_f32_32x32x16_bf16(a, b, c, 0, 0, 0)

constexpr float kQScale = 0.18033688011112042f;  // 0.125 * log2(e): softmax in log2 domain

__device__ __forceinline__ short f2bf(float f) {
  union { float f; unsigned u; } x; x.f = f;
  unsigned r = x.u + 0x7fffu + ((x.u >> 16) & 1u);
  return (short)(r >> 16);
}

__device__ __forceinline__ unsigned pk2(float a, float b) {
  __hip_bfloat162 h = __float22bfloat162_rn(make_float2(a, b));
  union { __hip_bfloat162 h; unsigned u; } c; c.h = h;
  return c.u;
}

__device__ __forceinline__ float fast_exp2(float x) {
  float r; asm("v_exp_f32 %0, %1" : "=v"(r) : "v"(x)); return r;
}

__device__ __forceinline__ void ld16(void* lds, const void* g) {
  __builtin_amdgcn_global_load_lds((const __attribute__((address_space(1))) void*)g,
                                   (__attribute__((address_space(3))) void*)lds, 16, 0, 0);
}

// ---------------- merged convert kernel: packed staging layouts for X, Wio AND Wout ----------------
// Packed layout (R8-proven): per (tile, kstep) an 8KB block [128 rows][4 chunks of 8 bf16]
// with the GEMM's chunk swizzle PRE-APPLIED -> GEMM stage reads are 1KB contiguous/wave-inst.
// X   : [z 0..2][mtile 0..31][kstep 0..31] blocks (24MB)
// Wio : [ntile 0..23][kstep 0..31] blocks (6MB)
// Wout: [ntile 0..7][kstep 0..31] blocks (2MB), base = W + 3145728 shorts
__global__ void conv_all(const float* __restrict__ q, const float* __restrict__ k,
                         const float* __restrict__ v, const float* __restrict__ w_in,
                         const float* __restrict__ w_out, short* __restrict__ X,
                         short* __restrict__ W) {
  int i = blockIdx.x * 256 + threadIdx.x;   // float4 index, 4194304 total
  float4 val;
  float s = 1.0f;
  short* dst;
  if (i < 3145728) {                        // qkv: 3 x 1048576
    int r = i >> 20, off = i & 0xFFFFF;
    const float* src = (r == 0) ? q : (r == 1) ? k : v;
    val = ((const float4*)src)[off];
    int m = off >> 8;                       // row 0..4095
    int kk = (off & 255) * 4;               // k element 0..1020, step 4
    int row = m & 127, mt = m >> 7;
    int ks = kk >> 5;
    int cs = ((kk >> 3) & 3) ^ ((row >> 1) & 3);
    dst = X + ((size_t)(r * 1024 + mt * 32 + ks) * 4096) + row * 32 + cs * 8 + (kk & 7);
  } else {                                  // weights: 1048576
    int j = i - 3145728;
    if (j < 786432) {
      val = ((const float4*)w_in)[j];
      if (j < 262144) s = kQScale;          // Wq rows (n < 1024)
      int n = j >> 8, kk = (j & 255) * 4;
      int row = n & 127, ntl = n >> 7;
      int ks = kk >> 5;
      int cs = ((kk >> 3) & 3) ^ ((row >> 1) & 3);
      dst = W + ((size_t)(ntl * 32 + ks) * 4096) + row * 32 + cs * 8 + (kk & 7);
    } else {
      int jj = j - 786432;                  // 0..262143
      val = ((const float4*)w_out)[jj];
      int n = jj >> 8, kk = (jj & 255) * 4;
      int row = n & 127, ntl = n >> 7;      // ntl 0..7
      int ks = kk >> 5;
      int cs = ((kk >> 3) & 3) ^ ((row >> 1) & 3);
      dst = W + 3145728 + ((size_t)(ntl * 32 + ks) * 4096) + row * 32 + cs * 8 + (kk & 7);
    }
  }
  short4v o;
  o.x = f2bf(val.x * s); o.y = f2bf(val.y * s); o.z = f2bf(val.z * s); o.w = f2bf(val.w * s);
  *(short4v*)dst = o;
}

// ---------------- NT GEMM: R0-proven body; BOTH modes stage from packed layouts ----------------
// MODE 0: A = X packed (z,mtile,kstep), B = Wio packed (ntile,kstep).   [R8-proven]
// MODE 1: A = Ows packed (mtile,kstep) written by attn, B = Wout packed. [R10-proven]
template <int MODE>
__global__ __launch_bounds__(256) void gemm_nt(
    const short* __restrict__ A, const short* __restrict__ B,
    const float* __restrict__ bias, float* __restrict__ fout,
    short* __restrict__ q_ws, short* __restrict__ k_ws, short* __restrict__ vt_ws) {
  const int K = 1024;
  __shared__ __align__(16) short As[4096];
  __shared__ __align__(16) short Bs[4096];
  int tid = threadIdx.x;
  int w = tid >> 6, lane = tid & 63, g = lane >> 4, ln = lane & 15;
  int wr = w >> 1, wc = w & 1;

  int n0, m0, z = 0;
  if (MODE == 0) {
    // flat 768: n_sub = fid/96, z = (fid%96)>>5, m = fid&31; sharers differ by 96 (mod 8 == 0)
    int fid = blockIdx.x;
    int n_sub = fid / 96;
    int r = fid % 96;
    z = r >> 5;
    int m = r & 31;
    n0 = (z * 8 + n_sub) * 128;
    m0 = m * 128;
  } else {
    int fid = blockIdx.x;
    n0 = (fid >> 5) * 128;
    m0 = (fid & 31) * 128;
  }

  // packed staging bases (per-lane): contiguous 1KB per wave-inst
  const short* aps;
  const short* bps;
  if (MODE == 0) {
    aps = A + (size_t)(z * 1024 + (m0 >> 7) * 32) * 4096 + w * 512 + lane * 8;
    bps = B + (size_t)(((n0 >> 7)) * 32) * 4096 + w * 512 + lane * 8;
  } else {
    aps = A + (size_t)((m0 >> 7) * 32) * 4096 + w * 512 + lane * 8;
    bps = B + (size_t)((n0 >> 7) * 32) * 4096 + w * 512 + lane * 8;
  }
  short* asd = As + w * 512;
  short* bsd = Bs + w * 512;

  f32x4 acc[4][4];
#pragma unroll
  for (int i = 0; i < 4; ++i)
#pragma unroll
    for (int j = 0; j < 4; ++j) acc[i][j] = (f32x4){0.f, 0.f, 0.f, 0.f};

  int rsw = (ln >> 1) & 3;                            // read-side chunk swizzle
  for (int kb = 0; kb < K; kb += 32) {
    __syncthreads();
    const short* ap = aps + (size_t)(kb >> 5) * 4096;
    const short* bp = bps + (size_t)(kb >> 5) * 4096;
    ld16(asd,        ap);
    ld16(asd + 2048, ap + 2048);
    ld16(bsd,        bp);
    ld16(bsd + 2048, bp + 2048);
    __syncthreads();
    bf16x8 af[4], bfr[4];
#pragma unroll
    for (int fm = 0; fm < 4; ++fm)
      af[fm] = *(const bf16x8*)&As[(wr * 64 + fm * 16 + ln) * 32 + (g ^ rsw) * 8];
#pragma unroll
    for (int fn = 0; fn < 4; ++fn)
      bfr[fn] = *(const bf16x8*)&Bs[(wc * 64 + fn * 16 + ln) * 32 + (g ^ rsw) * 8];
#pragma unroll
    for (int fm = 0; fm < 4; ++fm)
#pragma unroll
      for (int fn = 0; fn < 4; ++fn) acc[fm][fn] = MFMA16(af[fm], bfr[fn], acc[fm][fn]);
  }

#pragma unroll
  for (int fm = 0; fm < 4; ++fm) {
#pragma unroll
    for (int fn = 0; fn < 4; ++fn) {
      int col = n0 + wc * 64 + fn * 16 + ln;
#pragma unroll
      for (int i = 0; i < 4; ++i) {
        int m = m0 + wr * 64 + fm * 16 + g * 4 + i;
        float val = acc[fm][fn][i];
        if (MODE == 1) {
          fout[(size_t)m * 1024 + col] = val + bias[col];
        } else {
          int zc = col >> 10;
          int oe = col & 1023;
          float bval = bias[col];
          if (zc == 0) bval *= kQScale;
          short bv = f2bf(val + bval);
          int hh = oe >> 6, d = oe & 63;
          int l = m >> 1, nb = m & 1;
          int nh = nb * 16 + hh;
          if (zc == 0)      q_ws[((size_t)nh * 2048 + l) * 64 + d] = bv;
          else if (zc == 1) k_ws[((size_t)nh * 2048 + l) * 64 + d] = bv;
          else {
            int u = l & 15;
            int lp = (l & ~15) | (u & 3) | ((u & 4) << 1) | ((u & 8) >> 1);
            vt_ws[((size_t)nh * 64 + d) * 2048 + lp] = bv;
          }
        }
      }
    }
  }
}

// ---------------- flash attention v7: R10 body + 4-slot rings, 2-iter-deep counted vmcnt ----------------
// R11 change (single variable): K ring 3->4 slots (stage K t+4), V ring 3->4 slots (stage
// V t+3); steady-state wait vmcnt(8) (two iterations of loads stay in flight across each
// barrier; was vmcnt(4) = one). LDS 64KB/block -> 128KB per 2 blocks/CU (fits 160KB).
// FIFO audit: end of iter t must land K(t+2) [issued t-2] and V(t+1) [issued t-2]; ops
// issued after V(t+1) = {K(t+3),V(t+2),K(t+4),V(t+3)} x2 = 8 -> vmcnt(8).
// Tail: t==28 -> 6, t==29 -> 2, t==30 -> 0.  Slot liveness: K slots {t+1..t+4} mod 4
// distinct; V slots {t..t+3} mod 4 distinct; one barrier/iter orders slot reuse.
struct AttnCtx {
  const char* kg; const char* vg;      // next global stage pointers (call-A lane addr)
  char* klB; char* vlB;                // LDS bases
  char* kdst; char* vdst;              // wave-uniform LDS stage dest bases
  int lq, hi, swq;
  float lr;
};

__device__ __forceinline__ void attn_iter(
    int t, int& ksl, AttnCtx& c,
    f32x16& sCA, f32x16& sCB, f32x16& sNA, f32x16& sNB,
    f32x16 (&accO)[2], const bf16x8 (&qf)[4]) {
  // A: issue stages (K t+4 -> slot ksl(=t%4), V t+3 -> slot (ksl+3)&3)
  if (t <= 27) {
    ld16(c.kdst + ksl * 8192,        c.kg);
    ld16(c.kdst + ksl * 8192 + 4096, c.kg + 4096);
    c.kg += 8192;
  }
  if (t <= 28) {
    int vs = (ksl + 3) & 3;
    ld16(c.vdst + vs * 8192,        c.vg);
    ld16(c.vdst + vs * 8192 + 4096, c.vg + 131072);
    c.vg += 128;
  }

  // E': issue QK(t+1) MFMAs (independent of softmax below -> overlaps)
  if (t < 31) {
    int kr = (ksl + 1) & 3;
    const char* Kt = c.klB + kr * 8192;
#pragma unroll
    for (int i = 0; i < 16; ++i) { sNA[i] = 0.f; sNB[i] = 0.f; }
    __builtin_amdgcn_s_setprio(1);
#pragma unroll
    for (int kd = 0; kd < 4; ++kd) {
      int x = (32 * kd + 16 * c.hi) ^ c.swq;
      bf16x8 k0 = *(const bf16x8*)(Kt + c.lq * 128 + x);
      bf16x8 k1 = *(const bf16x8*)(Kt + (32 + c.lq) * 128 + x);
      sNA = MFMA32(k0, qf[kd], sNA);
      sNB = MFMA32(k1, qf[kd], sNB);
    }
    __builtin_amdgcn_s_setprio(0);
  }

  // B: static softmax on S(t): p = 2^s (shift-invariant; scores bounded)
#pragma unroll
  for (int i = 0; i < 16; ++i) { sCA[i] = fast_exp2(sCA[i]); sCB[i] = fast_exp2(sCB[i]); }
  float a0 = 0.f, a1 = 0.f, a2 = 0.f, a3 = 0.f;
#pragma unroll
  for (int i = 0; i < 4; ++i) {
    a0 += sCA[4 * i] + sCB[4 * i];
    a1 += sCA[4 * i + 1] + sCB[4 * i + 1];
    a2 += sCA[4 * i + 2] + sCB[4 * i + 2];
    a3 += sCA[4 * i + 3] + sCB[4 * i + 3];
  }
  c.lr += (a0 + a1) + (a2 + a3);

  bf16x8 pf[2][2];
  union PU { unsigned u[4]; bf16x8 v; };
#pragma unroll
  for (int ks = 0; ks < 2; ++ks) {
    PU a, b;
#pragma unroll
    for (int i = 0; i < 4; ++i) {
      a.u[i] = pk2(sCA[ks * 8 + 2 * i], sCA[ks * 8 + 2 * i + 1]);
      b.u[i] = pk2(sCB[ks * 8 + 2 * i], sCB[ks * 8 + 2 * i + 1]);
    }
    pf[0][ks] = a.v;
    pf[1][ks] = b.v;
  }

  // C: PV(t) from V slot ksl
  const char* Vtl = c.vlB + ksl * 8192;
  __builtin_amdgcn_s_setprio(1);
#pragma unroll
  for (int dblk = 0; dblk < 2; ++dblk) {
    const char* vrow = Vtl + (dblk * 32 + c.lq) * 128;
#pragma unroll
    for (int sblk = 0; sblk < 2; ++sblk) {
#pragma unroll
      for (int ks = 0; ks < 2; ++ks) {
        bf16x8 vf = *(const bf16x8*)(vrow + ((sblk * 64 + ks * 32 + c.hi * 16) ^ c.swq));
        accO[dblk] = MFMA32(vf, pf[sblk][ks], accO[dblk]);
      }
    }
  }
  __builtin_amdgcn_s_setprio(0);

  // D: counted vmem wait (2-iter-deep; never 0 in steady state) + raw barrier
  if (t < 28)       asm volatile("s_waitcnt vmcnt(8)" ::: "memory");
  else if (t == 28) asm volatile("s_waitcnt vmcnt(6)" ::: "memory");
  else if (t == 29) asm volatile("s_waitcnt vmcnt(2)" ::: "memory");
  else if (t == 30) asm volatile("s_waitcnt vmcnt(0)" ::: "memory");
  if (t < 31) __builtin_amdgcn_s_barrier();

  ksl = (ksl + 1) & 3;
}

__global__ __launch_bounds__(256, 2) void attn5(const short* __restrict__ Qws,
                                                const short* __restrict__ Kws,
                                                const short* __restrict__ Vt,
                                                short* __restrict__ Ows) {
  const int L = 2048;
  int bid = blockIdx.x;
  int nh = bid & 31, qt = bid >> 5;          // 16 q-tiles x 32 heads = 512 blocks
  int nb = nh >> 4, h = nh & 15;
  int tid = threadIdx.x;
  int w = tid >> 6, lane = tid & 63;
  int lq = lane & 31, hi = lane >> 5;

  __shared__ __align__(16) char Kl[4][8192];   // [64 s][64 d], XOR-swizzled rows, 4-slot ring
  __shared__ __align__(16) char Vl[4][8192];   // [64 d][64 s-permuted], XOR-swizzled rows

  int q0 = qt * 128 + w * 32;                  // 4 waves x 32 q-rows
  const short* Qb = Qws + (size_t)nh * L * 64;
  const char* Kb = (const char*)(Kws + (size_t)nh * L * 64);
  const char* Vb = (const char*)(Vt + (size_t)nh * 64 * L);

  bf16x8 qf[4];
#pragma unroll
  for (int kd = 0; kd < 4; ++kd)
    qf[kd] = *(const bf16x8*)(Qb + (size_t)(q0 + lq) * 64 + kd * 16 + hi * 8);

  // staging: call A covers tile rows 0..31 (rA = tid>>3), call B rows 32..63.
  int rA = tid >> 3, cc = (tid & 7) * 16;
  int swr = (rA & 7) << 4;                     // invariant under row+32

  AttnCtx c;
  c.kg = Kb + rA * 128 + (cc ^ swr);           // call B: +4096 (32 rows x 128B)
  c.vg = Vb + rA * 4096 + (cc ^ swr);          // call B: +131072 (32 d-rows x 4096B)
  c.klB = (char*)&Kl[0][0];
  c.vlB = (char*)&Vl[0][0];
  c.kdst = c.klB + w * 1024;
  c.vdst = c.vlB + w * 1024;
  c.lq = lq; c.hi = hi; c.swq = (lq & 7) << 4;
  c.lr = 0.f;

  // prologue stages: K0,K1,V0,K2,V1,K3,V2 (14 vmem ops)
  ld16(c.kdst,                c.kg);
  ld16(c.kdst + 4096,         c.kg + 4096);
  ld16(c.kdst + 8192,         c.kg + 8192);
  ld16(c.kdst + 8192 + 4096,  c.kg + 8192 + 4096);
  ld16(c.vdst,                c.vg);
  ld16(c.vdst + 4096,         c.vg + 131072);
  ld16(c.kdst + 16384,        c.kg + 16384);
  ld16(c.kdst + 16384 + 4096, c.kg + 16384 + 4096);
  ld16(c.vdst + 8192,         c.vg + 128);
  ld16(c.vdst + 8192 + 4096,  c.vg + 128 + 131072);
  ld16(c.kdst + 24576,        c.kg + 24576);
  ld16(c.kdst + 24576 + 4096, c.kg + 24576 + 4096);
  ld16(c.vdst + 16384,        c.vg + 256);
  ld16(c.vdst + 16384 + 4096, c.vg + 256 + 131072);
  c.kg += 4 * 8192;
  c.vg += 3 * 128;

  f32x16 accO[2];
#pragma unroll
  for (int i = 0; i < 16; ++i) { accO[0][i] = 0.f; accO[1][i] = 0.f; }
  f32x16 s0A, s0B, s1A, s1B;

  asm volatile("s_waitcnt vmcnt(12)" ::: "memory");  // K0 arrived; rest in flight
  __builtin_amdgcn_s_barrier();

  // prologue QK(0) -> s0
#pragma unroll
  for (int i = 0; i < 16; ++i) { s0A[i] = 0.f; s0B[i] = 0.f; }
  __builtin_amdgcn_s_setprio(1);
#pragma unroll
  for (int kd = 0; kd < 4; ++kd) {
    int x = (32 * kd + 16 * hi) ^ c.swq;
    bf16x8 k0 = *(const bf16x8*)(c.klB + lq * 128 + x);
    bf16x8 k1 = *(const bf16x8*)(c.klB + (32 + lq) * 128 + x);
    s0A = MFMA32(k0, qf[kd], s0A);
    s0B = MFMA32(k1, qf[kd], s0B);
  }
  __builtin_amdgcn_s_setprio(0);

  // seam: K1,V0 must be landed for iter 0 (ops after V0 = K2,V1,K3,V2 = 8); seam barrier
  // also orders all waves' slot-0 reads before iter-0's K4 stage into slot 0.
  asm volatile("s_waitcnt vmcnt(8)" ::: "memory");
  __builtin_amdgcn_s_barrier();

  int ksl = 0;
  for (int it = 0; it < 16; ++it) {
    attn_iter(2 * it,     ksl, c, s0A, s0B, s1A, s1B, accO, qf);
    attn_iter(2 * it + 1, ksl, c, s1A, s1B, s0A, s0B, accO, qf);
  }

  // epilogue: l = own half + partner half; O in PACKED staging layout for gemm_nt<1>:
  // m = qrow*2+nb, col c = h*64 + dblk*32 + grp*8 + hi*4
  // block = (m>>7)*32 + h*2 + dblk ; row = m&127 ; chunk = grp
  // dst = block*4096 + row*32 + (grp ^ ((row>>1)&3))*8 + hi*4
  float lr = c.lr + __shfl_xor(c.lr, 32);
  float inv = 1.0f / lr;
  int qrow = q0 + lq;
  int m = qrow * 2 + nb;
  int row = m & 127;
  short* obase = Ows + ((size_t)((m >> 7) * 32 + h * 2) * 4096) + row * 32 + hi * 4;
  int rs3 = (row >> 1) & 3;
#pragma unroll
  for (int dblk = 0; dblk < 2; ++dblk) {
#pragma unroll
    for (int grp = 0; grp < 4; ++grp) {
      short4v o;
      o.x = f2bf(accO[dblk][grp * 4 + 0] * inv);
      o.y = f2bf(accO[dblk][grp * 4 + 1] * inv);
      o.z = f2bf(accO[dblk][grp * 4 + 2] * inv);
      o.w = f2bf(accO[dblk][grp * 4 + 3] * inv);
      *(short4v*)(obase + dblk * 4096 + (grp ^ rs3) * 8) = o;
    }
  }
}

// ---------------- launch ----------------
extern "C" void kernel_launch(void* const* d_in, const int* in_sizes, int n_in,
                              void* d_out, int out_size, void* d_ws, size_t ws_size,
                              hipStream_t stream) {
  const float* q     = (const float*)d_in[0];
  const float* k     = (const float*)d_in[1];
  const float* v     = (const float*)d_in[2];
  const float* w_in  = (const float*)d_in[3];
  const float* b_in  = (const float*)d_in[4];
  const float* w_out = (const float*)d_in[5];
  const float* b_out = (const float*)d_in[6];
  float* out = (float*)d_out;
  char* ws = (char*)d_ws;

  short* X    = (short*)(ws);                  // 3*4096*1024 bf16 (packed staging layout)
  short* Wio  = (short*)(ws + 25165824);       // 3072*1024 (packed staging layout)
  short* Wout = (short*)(ws + 31457280);       // 1024*1024 (packed staging layout)
  short* Qws  = (short*)(ws + 33554432);       // [32 nh][2048][64]
  short* Kws  = (short*)(ws + 41943040);       // [32 nh][2048][64]
  short* Vt   = (short*)(ws + 50331648);       // [32 nh][64][2048] (s-permuted)
  short* Ows  = (short*)(ws + 58720256);       // [4096][1024] packed as [mtile][kstep] blocks

  conv_all<<<16384, 256, 0, stream>>>(q, k, v, w_in, w_out, X, Wio);
  gemm_nt<0><<<768, 256, 0, stream>>>(X, Wio, b_in, nullptr, Qws, Kws, Vt);
  attn5<<<512, 256, 0, stream>>>(Qws, Kws, Vt, Ows);
  gemm_nt<1><<<256, 256, 0, stream>>>(Ows, Wout, b_out, out, nullptr, nullptr, nullptr);
}